// Round 3
// baseline (102.145 us; speedup 1.0000x reference)
//
#include <hip/hip_runtime.h>

#define H_ 128
#define W_ 128
#define HW 16384
#define C_ 64
#define O_ 64
#define N_ 8

typedef __attribute__((ext_vector_type(4))) float f32x4;
typedef __attribute__((ext_vector_type(2))) float f32x2;
typedef __attribute__((ext_vector_type(8))) short short8;

__device__ __forceinline__ unsigned short f2bf(float f) {
    unsigned b = __float_as_uint(f);
    return (unsigned short)((b + 0x7fffu + ((b >> 16) & 1u)) >> 16);
}
// unpack 2 packed bf16 (lo,hi of u32) into a float2
__device__ __forceinline__ f32x2 bf2f2(unsigned u) {
    f32x2 r;
    r.x = __uint_as_float(u << 16);
    r.y = __uint_as_float(u & 0xffff0000u);
    return r;
}
// pack float2 -> 2 bf16 in one u32 (RNE) via HW cvt_pk
__device__ __forceinline__ unsigned cvtpk(f32x2 v) {
    unsigned r;
    asm("v_cvt_pk_bf16_f32 %0, %1, %2" : "=v"(r) : "v"(v.x), "v"(v.y));
    return r;
}

// ---- prep 1: x NCHW fp32 -> xt NHWC bf16 ----
__global__ __launch_bounds__(256) void nchw2nhwc(const float* __restrict__ x,
                                                 unsigned short* __restrict__ xt) {
    const int bid = blockIdx.x;
    const int wt = bid & 3, h = (bid >> 2) & 127, n = bid >> 9;
    const int w0 = wt * 32;
    __shared__ unsigned short tile[32][65];
    const int tid = threadIdx.x;
    const int wl = tid & 31, cg = tid >> 5;
#pragma unroll
    for (int r = 0; r < 8; ++r) {
        const int c = cg * 8 + r;
        const float v = x[(((size_t)(n * 64 + c) * 128 + h) * 128) + w0 + wl];
        tile[wl][c] = f2bf(v);
    }
    __syncthreads();
    const int c2 = tid & 63, wg = tid >> 6;
#pragma unroll
    for (int r = 0; r < 8; ++r) {
        const int w = wg * 8 + r;
        xt[(((size_t)(n * 128 + h) * 128 + w0 + w) << 6) + c2] = tile[w][c2];
    }
}

// ---- prep 2: weight [O][C][3][3] fp32 -> B-fragment-packed bf16 ----
// ushort idx = q*512 + lane*8 + i ; q = (j*2+h)*4 + ot
// o = ot*16 + (lane&15) ; c = h*32 + (lane>>4)*8 + i
__global__ void bpack_kernel(const float* __restrict__ w, unsigned short* __restrict__ bp) {
    const int idx = blockIdx.x * 256 + threadIdx.x;
    if (idx >= 36864) return;
    const int i = idx & 7;
    const int lane = (idx >> 3) & 63;
    const int ot = (idx >> 9) & 3;
    const int h = (idx >> 11) & 1;
    const int j = idx >> 12;
    const int o = ot * 16 + (lane & 15);
    const int c = h * 32 + (lane >> 4) * 8 + i;
    bp[idx] = f2bf(w[(o * 64 + c) * 9 + j]);
}

// ---- main: implicit GEMM, one wave = one 16-pixel x 64-o strip, B from global ----
__global__ __launch_bounds__(256, 4) void dcn_mfma(const unsigned short* __restrict__ xt,
                                                   const float* __restrict__ off,
                                                   const unsigned short* __restrict__ bp,
                                                   float* __restrict__ out) {
    const int tid = threadIdx.x;
    const int lane = tid & 63;
    const int wid = tid >> 6;
    const int lrow = lane & 15;   // M row (pixel) in A; o in epilogue
    const int lgrp = lane >> 4;   // k-group

    const int strip = blockIdx.x * 4 + wid;
    const int n = strip >> 10;
    const int p0 = (strip & 1023) << 4;
    const int pix = p0 + lrow;
    const int ho = pix >> 7;
    const int wo = pix & 127;

    // preload all 18 offset scalars for this pixel (breaks per-j load->use chain)
    float offs[18];
    {
        const float* offp = off + (size_t)n * 18 * HW + pix;
#pragma unroll
        for (int ch = 0; ch < 18; ++ch) offs[ch] = offp[(size_t)ch * HW];
    }

    f32x4 acc0 = {0.f,0.f,0.f,0.f}, acc1 = {0.f,0.f,0.f,0.f};
    f32x4 acc2 = {0.f,0.f,0.f,0.f}, acc3 = {0.f,0.f,0.f,0.f};

    const unsigned short* xn = xt + (size_t)n * (HW * 64);
    const short8* bg = (const short8*)bp;

#pragma unroll
    for (int j = 0; j < 9; ++j) {
        const int kh = j / 3, kw = j % 3;
        const float oy = offs[2 * j];
        const float ox = offs[2 * j + 1];
        const float py = (float)(ho - 1 + kh) + oy;
        const float px = (float)(wo - 1 + kw) + ox;
        const float y0f = floorf(py), x0f = floorf(px);
        const float wy = py - y0f, wx = px - x0f;
        const int y0 = (int)y0f, x0 = (int)x0f;
        const bool vy0 = (unsigned)y0 < (unsigned)H_;
        const bool vy1 = (unsigned)(y0 + 1) < (unsigned)H_;
        const bool vx0 = (unsigned)x0 < (unsigned)W_;
        const bool vx1 = (unsigned)(x0 + 1) < (unsigned)W_;
        const int y0c = min(max(y0, 0), H_ - 1);
        const int y1c = min(max(y0 + 1, 0), H_ - 1);
        const int x0c = min(max(x0, 0), W_ - 1);
        const int x1c = min(max(x0 + 1, 0), W_ - 1);
        const float s00 = (1.f - wy) * (1.f - wx) * ((vy0 & vx0) ? 1.f : 0.f);
        const float s01 = (1.f - wy) * wx * ((vy0 & vx1) ? 1.f : 0.f);
        const float s10 = wy * (1.f - wx) * ((vy1 & vx0) ? 1.f : 0.f);
        const float s11 = wy * wx * ((vy1 & vx1) ? 1.f : 0.f);
        const f32x2 w00 = {s00, s00}, w01 = {s01, s01}, w10 = {s10, s10}, w11 = {s11, s11};

        const unsigned short* b00 = xn + (size_t)(y0c * W_ + x0c) * 64;
        const int dxo = (x1c - x0c) * 64;
        const int dyo = (y1c - y0c) * (W_ * 64);

#pragma unroll
        for (int h = 0; h < 2; ++h) {
            const int c0 = h * 32 + lgrp * 8;
            const uint4 u00 = *(const uint4*)(b00 + c0);
            const uint4 u01 = *(const uint4*)(b00 + dxo + c0);
            const uint4 u10 = *(const uint4*)(b00 + dyo + c0);
            const uint4 u11 = *(const uint4*)(b00 + dyo + dxo + c0);
            uint4 av;
            {
                f32x2 s = bf2f2(u00.x) * w00 + bf2f2(u01.x) * w01 + bf2f2(u10.x) * w10 + bf2f2(u11.x) * w11;
                av.x = cvtpk(s);
            }
            {
                f32x2 s = bf2f2(u00.y) * w00 + bf2f2(u01.y) * w01 + bf2f2(u10.y) * w10 + bf2f2(u11.y) * w11;
                av.y = cvtpk(s);
            }
            {
                f32x2 s = bf2f2(u00.z) * w00 + bf2f2(u01.z) * w01 + bf2f2(u10.z) * w10 + bf2f2(u11.z) * w11;
                av.z = cvtpk(s);
            }
            {
                f32x2 s = bf2f2(u00.w) * w00 + bf2f2(u01.w) * w01 + bf2f2(u10.w) * w10 + bf2f2(u11.w) * w11;
                av.w = cvtpk(s);
            }
            union { uint4 u; short8 v; } A;
            A.u = av;
            const int fb = ((j * 2 + h) * 4) * 64 + lane;
            acc0 = __builtin_amdgcn_mfma_f32_16x16x32_bf16(A.v, bg[fb],       acc0, 0, 0, 0);
            acc1 = __builtin_amdgcn_mfma_f32_16x16x32_bf16(A.v, bg[fb + 64],  acc1, 0, 0, 0);
            acc2 = __builtin_amdgcn_mfma_f32_16x16x32_bf16(A.v, bg[fb + 128], acc2, 0, 0, 0);
            acc3 = __builtin_amdgcn_mfma_f32_16x16x32_bf16(A.v, bg[fb + 192], acc3, 0, 0, 0);
        }
    }

    // epilogue (mapping verified in round 2): o = q*16+lrow plane, pixel = p0 + lgrp*4 + r
    float* opb = out + (size_t)n * (O_ * HW) + p0 + lgrp * 4;
    *(f32x4*)(opb + (size_t)(0 * 16 + lrow) * HW) = acc0;
    *(f32x4*)(opb + (size_t)(1 * 16 + lrow) * HW) = acc1;
    *(f32x4*)(opb + (size_t)(2 * 16 + lrow) * HW) = acc2;
    *(f32x4*)(opb + (size_t)(3 * 16 + lrow) * HW) = acc3;
}

extern "C" void kernel_launch(void* const* d_in, const int* in_sizes, int n_in,
                              void* d_out, int out_size, void* d_ws, size_t ws_size,
                              hipStream_t stream) {
    const float* x = (const float*)d_in[0];
    const float* off = (const float*)d_in[1];
    const float* w = (const float*)d_in[2];
    float* out = (float*)d_out;

    unsigned short* bp = (unsigned short*)d_ws;                  // 73728 B
    unsigned short* xt = (unsigned short*)((char*)d_ws + 73728); // 16.8 MB

    bpack_kernel<<<144, 256, 0, stream>>>(w, bp);
    nchw2nhwc<<<4096, 256, 0, stream>>>(x, xt);

    const int strips = N_ * HW / 16;  // 8192 waves
    dcn_mfma<<<strips / 4, 256, 0, stream>>>(xt, off, bp, out);
}

// Round 4
// 100.672 us; speedup vs baseline: 1.0146x; 1.0146x over previous
//
#include <hip/hip_runtime.h>

#define H_ 128
#define W_ 128
#define HW 16384
#define C_ 64
#define O_ 64
#define N_ 8

typedef __attribute__((ext_vector_type(4))) float f32x4;
typedef __attribute__((ext_vector_type(2))) _Float16 f16x2;
typedef __attribute__((ext_vector_type(8))) _Float16 f16x8;

__device__ __forceinline__ unsigned short f2h(float f) {
    union { _Float16 h; unsigned short u; } c;
    c.h = (_Float16)f;
    return c.u;
}

// ---- prep 1: x NCHW fp32 -> xt NHWC f16 ----
__global__ __launch_bounds__(256) void nchw2nhwc(const float* __restrict__ x,
                                                 unsigned short* __restrict__ xt) {
    const int bid = blockIdx.x;
    const int wt = bid & 3, h = (bid >> 2) & 127, n = bid >> 9;
    const int w0 = wt * 32;
    __shared__ unsigned short tile[32][65];
    const int tid = threadIdx.x;
    const int wl = tid & 31, cg = tid >> 5;
#pragma unroll
    for (int r = 0; r < 8; ++r) {
        const int c = cg * 8 + r;
        const float v = x[(((size_t)(n * 64 + c) * 128 + h) * 128) + w0 + wl];
        tile[wl][c] = f2h(v);
    }
    __syncthreads();
    const int c2 = tid & 63, wg = tid >> 6;
#pragma unroll
    for (int r = 0; r < 8; ++r) {
        const int w = wg * 8 + r;
        xt[(((size_t)(n * 128 + h) * 128 + w0 + w) << 6) + c2] = tile[w][c2];
    }
}

// ---- prep 2: weight [O][C][3][3] fp32 -> B-fragment-packed f16 ----
// ushort idx = q*512 + lane*8 + i ; q = (j*2+h)*4 + ot
// o = ot*16 + (lane&15) ; c = h*32 + (lane>>4)*8 + i
__global__ void bpack_kernel(const float* __restrict__ w, unsigned short* __restrict__ bp) {
    const int idx = blockIdx.x * 256 + threadIdx.x;
    if (idx >= 36864) return;
    const int i = idx & 7;
    const int lane = (idx >> 3) & 63;
    const int ot = (idx >> 9) & 3;
    const int h = (idx >> 11) & 1;
    const int j = idx >> 12;
    const int o = ot * 16 + (lane & 15);
    const int c = h * 32 + (lane >> 4) * 8 + i;
    bp[idx] = f2h(w[(o * 64 + c) * 9 + j]);
}

// ---- main: implicit GEMM, one wave = TWO 16-pixel x 64-o strips (f16 interp) ----
__global__ __launch_bounds__(256, 4) void dcn_mfma(const unsigned short* __restrict__ xt,
                                                   const float* __restrict__ off,
                                                   const unsigned short* __restrict__ bp,
                                                   float* __restrict__ out) {
    const int tid = threadIdx.x;
    const int lane = tid & 63;
    const int wid = tid >> 6;
    const int lrow = lane & 15;   // pixel row in A-tile; o in epilogue
    const int lgrp = lane >> 4;   // k-group

    const int wave = blockIdx.x * 4 + wid;   // 4096 waves, 32 pixels each
    const int n = wave >> 9;
    const int pbase = (wave & 511) << 5;

    f32x4 acc[2][4];
#pragma unroll
    for (int s = 0; s < 2; ++s)
#pragma unroll
        for (int q = 0; q < 4; ++q) acc[s][q] = (f32x4){0.f, 0.f, 0.f, 0.f};

    const unsigned short* xn = xt + (size_t)n * (HW * 64);
    const f16x8* bg = (const f16x8*)bp;
    const float* offn = off + (size_t)n * 18 * HW;

    int pix[2], ho[2], wo[2];
#pragma unroll
    for (int s = 0; s < 2; ++s) {
        pix[s] = pbase + s * 16 + lrow;
        ho[s] = pix[s] >> 7;
        wo[s] = pix[s] & 127;
    }

#pragma unroll
    for (int j = 0; j < 9; ++j) {
        const int kh = j / 3, kw = j % 3;

        const unsigned short* base[2];
        int dxo[2], dyo[2];
        f16x2 W00[2], W01[2], W10[2], W11[2];

#pragma unroll
        for (int s = 0; s < 2; ++s) {
            const float oy = offn[(size_t)(2 * j) * HW + pix[s]];
            const float ox = offn[(size_t)(2 * j + 1) * HW + pix[s]];
            const float py = (float)(ho[s] - 1 + kh) + oy;
            const float px = (float)(wo[s] - 1 + kw) + ox;
            const float y0f = floorf(py), x0f = floorf(px);
            const float wy = py - y0f, wx = px - x0f;
            const int y0 = (int)y0f, x0 = (int)x0f;
            const bool vy0 = (unsigned)y0 < (unsigned)H_;
            const bool vy1 = (unsigned)(y0 + 1) < (unsigned)H_;
            const bool vx0 = (unsigned)x0 < (unsigned)W_;
            const bool vx1 = (unsigned)(x0 + 1) < (unsigned)W_;
            const int y0c = min(max(y0, 0), H_ - 1);
            const int y1c = min(max(y0 + 1, 0), H_ - 1);
            const int x0c = min(max(x0, 0), W_ - 1);
            const int x1c = min(max(x0 + 1, 0), W_ - 1);
            const float s00 = (1.f - wy) * (1.f - wx) * ((vy0 & vx0) ? 1.f : 0.f);
            const float s01 = (1.f - wy) * wx * ((vy0 & vx1) ? 1.f : 0.f);
            const float s10 = wy * (1.f - wx) * ((vy1 & vx0) ? 1.f : 0.f);
            const float s11 = wy * wx * ((vy1 & vx1) ? 1.f : 0.f);
            const _Float16 h00 = (_Float16)s00, h01 = (_Float16)s01;
            const _Float16 h10 = (_Float16)s10, h11 = (_Float16)s11;
            W00[s] = (f16x2){h00, h00};
            W01[s] = (f16x2){h01, h01};
            W10[s] = (f16x2){h10, h10};
            W11[s] = (f16x2){h11, h11};
            base[s] = xn + (size_t)(y0c * W_ + x0c) * 64;
            dxo[s] = (x1c - x0c) * 64;
            dyo[s] = (y1c - y0c) * (W_ * 64);
        }

#pragma unroll
        for (int h = 0; h < 2; ++h) {
            const int fb = ((j * 2 + h) * 4) * 64 + lane;
            const f16x8 b0 = bg[fb];
            const f16x8 b1 = bg[fb + 64];
            const f16x8 b2 = bg[fb + 128];
            const f16x8 b3 = bg[fb + 192];
#pragma unroll
            for (int s = 0; s < 2; ++s) {
                const unsigned short* p = base[s] + h * 32 + lgrp * 8;
                union { uint4 u; f16x2 h2[4]; f16x8 v; } T00, T01, T10, T11, A;
                T00.u = *(const uint4*)p;
                T01.u = *(const uint4*)(p + dxo[s]);
                T10.u = *(const uint4*)(p + dyo[s]);
                T11.u = *(const uint4*)(p + dyo[s] + dxo[s]);
#pragma unroll
                for (int k = 0; k < 4; ++k)
                    A.h2[k] = T00.h2[k] * W00[s] + T01.h2[k] * W01[s]
                            + T10.h2[k] * W10[s] + T11.h2[k] * W11[s];
                acc[s][0] = __builtin_amdgcn_mfma_f32_16x16x32_f16(A.v, b0, acc[s][0], 0, 0, 0);
                acc[s][1] = __builtin_amdgcn_mfma_f32_16x16x32_f16(A.v, b1, acc[s][1], 0, 0, 0);
                acc[s][2] = __builtin_amdgcn_mfma_f32_16x16x32_f16(A.v, b2, acc[s][2], 0, 0, 0);
                acc[s][3] = __builtin_amdgcn_mfma_f32_16x16x32_f16(A.v, b3, acc[s][3], 0, 0, 0);
            }
        }
    }

    // epilogue: per strip, o = q*16 + lrow plane, pixel = pbase + s*16 + lgrp*4 + r
#pragma unroll
    for (int s = 0; s < 2; ++s) {
        float* opb = out + (size_t)n * (O_ * HW) + pbase + s * 16 + lgrp * 4;
        *(f32x4*)(opb + (size_t)(0 * 16 + lrow) * HW) = acc[s][0];
        *(f32x4*)(opb + (size_t)(1 * 16 + lrow) * HW) = acc[s][1];
        *(f32x4*)(opb + (size_t)(2 * 16 + lrow) * HW) = acc[s][2];
        *(f32x4*)(opb + (size_t)(3 * 16 + lrow) * HW) = acc[s][3];
    }
}

extern "C" void kernel_launch(void* const* d_in, const int* in_sizes, int n_in,
                              void* d_out, int out_size, void* d_ws, size_t ws_size,
                              hipStream_t stream) {
    const float* x = (const float*)d_in[0];
    const float* off = (const float*)d_in[1];
    const float* w = (const float*)d_in[2];
    float* out = (float*)d_out;

    unsigned short* bp = (unsigned short*)d_ws;                  // 73728 B
    unsigned short* xt = (unsigned short*)((char*)d_ws + 73728); // 16.8 MB

    bpack_kernel<<<144, 256, 0, stream>>>(w, bp);
    nchw2nhwc<<<4096, 256, 0, stream>>>(x, xt);

    const int waves = N_ * HW / 32;   // 4096
    dcn_mfma<<<waves / 4, 256, 0, stream>>>(xt, off, bp, out);
}

// Round 5
// 92.394 us; speedup vs baseline: 1.1055x; 1.0896x over previous
//
#include <hip/hip_runtime.h>

#define H_ 128
#define W_ 128
#define HW 16384
#define C_ 64
#define O_ 64
#define N_ 8

typedef __attribute__((ext_vector_type(4))) float f32x4;
typedef __attribute__((ext_vector_type(2))) _Float16 f16x2;
typedef __attribute__((ext_vector_type(8))) _Float16 f16x8;

__device__ __forceinline__ unsigned short f2h(float f) {
    union { _Float16 h; unsigned short u; } c;
    c.h = (_Float16)f;
    return c.u;
}

// ---- prep 1: x NCHW fp32 -> xt NHWC f16, XCD-aligned (n = bid&7) ----
__global__ __launch_bounds__(256) void nchw2nhwc(const float* __restrict__ x,
                                                 unsigned short* __restrict__ xt) {
    const int bid = blockIdx.x;
    const int n = bid & 7;              // lands on XCD n (round-robin dispatch)
    const int rest = bid >> 3;          // 0..511
    const int wt = rest & 3, h = rest >> 2;
    const int w0 = wt * 32;
    __shared__ unsigned short tile[32][65];
    const int tid = threadIdx.x;
    const int wl = tid & 31, cg = tid >> 5;
#pragma unroll
    for (int r = 0; r < 8; ++r) {
        const int c = cg * 8 + r;
        const float v = x[(((size_t)(n * 64 + c) * 128 + h) * 128) + w0 + wl];
        tile[wl][c] = f2h(v);
    }
    __syncthreads();
    const int c2 = tid & 63, wg = tid >> 6;
#pragma unroll
    for (int r = 0; r < 8; ++r) {
        const int w = wg * 8 + r;
        xt[(((size_t)(n * 128 + h) * 128 + w0 + w) << 6) + c2] = tile[w][c2];
    }
}

// ---- prep 2: weight [O][C][3][3] fp32 -> B-fragment-packed f16 ----
__global__ void bpack_kernel(const float* __restrict__ w, unsigned short* __restrict__ bp) {
    const int idx = blockIdx.x * 256 + threadIdx.x;
    if (idx >= 36864) return;
    const int i = idx & 7;
    const int lane = (idx >> 3) & 63;
    const int ot = (idx >> 9) & 3;
    const int h = (idx >> 11) & 1;
    const int j = idx >> 12;
    const int o = ot * 16 + (lane & 15);
    const int c = h * 32 + (lane >> 4) * 8 + i;
    bp[idx] = f2h(w[(o * 64 + c) * 9 + j]);
}

// ---- main: implicit GEMM; one wave = two 16px strips; image n pinned to XCD n ----
__global__ __launch_bounds__(256, 3) void dcn_mfma(const unsigned short* __restrict__ xt,
                                                   const float* __restrict__ off,
                                                   const unsigned short* __restrict__ bp,
                                                   float* __restrict__ out) {
    const int tid = threadIdx.x;
    const int lane = tid & 63;
    const int wid = tid >> 6;
    const int lrow = lane & 15;   // pixel row in A-tile; o in epilogue
    const int lgrp = lane >> 4;   // k-group

    const int bid = blockIdx.x;
    const int n = bid & 7;                     // XCD-pinned image
    const int sidx = (bid >> 3) * 4 + wid;     // 0..511 (32-px groups)
    const int pbase = sidx << 5;

    const unsigned char* xb = (const unsigned char*)(xt + (size_t)n * (HW * 64));
    const f16x8* bg = (const f16x8*)bp;
    const float* offn = off + (size_t)n * 18 * HW;

    int pix[2], ho[2], wo[2];
#pragma unroll
    for (int s = 0; s < 2; ++s) {
        pix[s] = pbase + s * 16 + lrow;
        ho[s] = pix[s] >> 7;
        wo[s] = pix[s] & 127;
    }

    // preload all 36 offset scalars (breaks the per-j load->use chain head)
    float offs[2][18];
#pragma unroll
    for (int s = 0; s < 2; ++s)
#pragma unroll
        for (int ch = 0; ch < 18; ++ch)
            offs[s][ch] = offn[(size_t)ch * HW + pix[s]];

    f32x4 acc[2][4];
#pragma unroll
    for (int s = 0; s < 2; ++s)
#pragma unroll
        for (int q = 0; q < 4; ++q) acc[s][q] = (f32x4){0.f, 0.f, 0.f, 0.f};

#pragma unroll
    for (int j = 0; j < 9; ++j) {
        const int kh = j / 3, kw = j % 3;

        unsigned vb[2];
        int dxo[2], dyo[2];
        f16x2 W00[2], W01[2], W10[2], W11[2];

#pragma unroll
        for (int s = 0; s < 2; ++s) {
            const float oy = offs[s][2 * j];
            const float ox = offs[s][2 * j + 1];
            const float py = (float)(ho[s] - 1 + kh) + oy;
            const float px = (float)(wo[s] - 1 + kw) + ox;
            const float y0f = floorf(py), x0f = floorf(px);
            const float wy = py - y0f, wx = px - x0f;
            const int y0 = (int)y0f, x0 = (int)x0f;
            const bool vy0 = (unsigned)y0 < (unsigned)H_;
            const bool vy1 = (unsigned)(y0 + 1) < (unsigned)H_;
            const bool vx0 = (unsigned)x0 < (unsigned)W_;
            const bool vx1 = (unsigned)(x0 + 1) < (unsigned)W_;
            const int y0c = min(max(y0, 0), H_ - 1);
            const int y1c = min(max(y0 + 1, 0), H_ - 1);
            const int x0c = min(max(x0, 0), W_ - 1);
            const int x1c = min(max(x0 + 1, 0), W_ - 1);
            const float s00 = (1.f - wy) * (1.f - wx) * ((vy0 & vx0) ? 1.f : 0.f);
            const float s01 = (1.f - wy) * wx * ((vy0 & vx1) ? 1.f : 0.f);
            const float s10 = wy * (1.f - wx) * ((vy1 & vx0) ? 1.f : 0.f);
            const float s11 = wy * wx * ((vy1 & vx1) ? 1.f : 0.f);
            const _Float16 h00 = (_Float16)s00, h01 = (_Float16)s01;
            const _Float16 h10 = (_Float16)s10, h11 = (_Float16)s11;
            W00[s] = (f16x2){h00, h00};
            W01[s] = (f16x2){h01, h01};
            W10[s] = (f16x2){h10, h10};
            W11[s] = (f16x2){h11, h11};
            vb[s] = (unsigned)((((ho[s] - 1 + kh) >= 0 ? y0c : y0c) * W_ + x0c) * 128 + lgrp * 16);
            vb[s] = (unsigned)((y0c * W_ + x0c) * 128 + lgrp * 16);   // 32-bit byte offset
            dxo[s] = (x1c - x0c) * 128;
            dyo[s] = (y1c - y0c) * (W_ * 128);
        }

#pragma unroll
        for (int h = 0; h < 2; ++h) {
            const int fb = ((j * 2 + h) * 4) * 64 + lane;
            const f16x8 b0 = bg[fb];
            const f16x8 b1 = bg[fb + 64];
            const f16x8 b2 = bg[fb + 128];
            const f16x8 b3 = bg[fb + 192];
#pragma unroll
            for (int s = 0; s < 2; ++s) {
                const unsigned char* p = xb + vb[s] + h * 64;
                union { uint4 u; f16x2 h2[4]; f16x8 v; } T00, T01, T10, T11, A;
                T00.u = *(const uint4*)p;
                T01.u = *(const uint4*)(p + dxo[s]);
                T10.u = *(const uint4*)(p + dyo[s]);
                T11.u = *(const uint4*)(p + dyo[s] + dxo[s]);
#pragma unroll
                for (int k = 0; k < 4; ++k)
                    A.h2[k] = T00.h2[k] * W00[s] + T01.h2[k] * W01[s]
                            + T10.h2[k] * W10[s] + T11.h2[k] * W11[s];
                acc[s][0] = __builtin_amdgcn_mfma_f32_16x16x32_f16(A.v, b0, acc[s][0], 0, 0, 0);
                acc[s][1] = __builtin_amdgcn_mfma_f32_16x16x32_f16(A.v, b1, acc[s][1], 0, 0, 0);
                acc[s][2] = __builtin_amdgcn_mfma_f32_16x16x32_f16(A.v, b2, acc[s][2], 0, 0, 0);
                acc[s][3] = __builtin_amdgcn_mfma_f32_16x16x32_f16(A.v, b3, acc[s][3], 0, 0, 0);
            }
        }
    }

    // epilogue: per strip, o = q*16 + lrow plane, pixel = pbase + s*16 + lgrp*4 + r
#pragma unroll
    for (int s = 0; s < 2; ++s) {
        float* opb = out + (size_t)n * (O_ * HW) + pbase + s * 16 + lgrp * 4;
        *(f32x4*)(opb + (size_t)(0 * 16 + lrow) * HW) = acc[s][0];
        *(f32x4*)(opb + (size_t)(1 * 16 + lrow) * HW) = acc[s][1];
        *(f32x4*)(opb + (size_t)(2 * 16 + lrow) * HW) = acc[s][2];
        *(f32x4*)(opb + (size_t)(3 * 16 + lrow) * HW) = acc[s][3];
    }
}

extern "C" void kernel_launch(void* const* d_in, const int* in_sizes, int n_in,
                              void* d_out, int out_size, void* d_ws, size_t ws_size,
                              hipStream_t stream) {
    const float* x = (const float*)d_in[0];
    const float* off = (const float*)d_in[1];
    const float* w = (const float*)d_in[2];
    float* out = (float*)d_out;

    unsigned short* bp = (unsigned short*)d_ws;                  // 73728 B
    unsigned short* xt = (unsigned short*)((char*)d_ws + 73728); // 16.8 MB

    bpack_kernel<<<144, 256, 0, stream>>>(w, bp);
    nchw2nhwc<<<4096, 256, 0, stream>>>(x, xt);

    dcn_mfma<<<1024, 256, 0, stream>>>(xt, off, bp, out);
}

// Round 7
// 70.730 us; speedup vs baseline: 1.4442x; 1.3063x over previous
//
#include <hip/hip_runtime.h>

#define H_ 128
#define W_ 128
#define HW 16384
#define C_ 64
#define O_ 64
#define N_ 8

typedef __attribute__((ext_vector_type(4))) float f32x4;
typedef __attribute__((ext_vector_type(2))) _Float16 f16x2;
typedef __attribute__((ext_vector_type(8))) _Float16 f16x8;

__device__ __forceinline__ unsigned short f2h(float f) {
    union { _Float16 h; unsigned short u; } c;
    c.h = (_Float16)f;
    return c.u;
}

// ---- prep 1: x NCHW fp32 -> xt NHWC f16, XCD-aligned (n = bid&7) ----
__global__ __launch_bounds__(256) void nchw2nhwc(const float* __restrict__ x,
                                                 unsigned short* __restrict__ xt) {
    const int bid = blockIdx.x;
    const int n = bid & 7;
    const int rest = bid >> 3;
    const int wt = rest & 3, h = rest >> 2;
    const int w0 = wt * 32;
    __shared__ unsigned short tile[32][65];
    const int tid = threadIdx.x;
    const int wl = tid & 31, cg = tid >> 5;
#pragma unroll
    for (int r = 0; r < 8; ++r) {
        const int c = cg * 8 + r;
        const float v = x[(((size_t)(n * 64 + c) * 128 + h) * 128) + w0 + wl];
        tile[wl][c] = f2h(v);
    }
    __syncthreads();
    const int c2 = tid & 63, wg = tid >> 6;
#pragma unroll
    for (int r = 0; r < 8; ++r) {
        const int w = wg * 8 + r;
        xt[(((size_t)(n * 128 + h) * 128 + w0 + w) << 6) + c2] = tile[w][c2];
    }
}

// ---- prep 2: weight [O][C][3][3] fp32 -> B-fragment-packed f16 ----
// ushort idx = q*512 + lane*8 + i ; q = (j*2+h)*4 + ot
// o = ot*16 + (lane&15) ; c = h*32 + (lane>>4)*8 + i
__global__ void bpack_kernel(const float* __restrict__ w, unsigned short* __restrict__ bp) {
    const int idx = blockIdx.x * 256 + threadIdx.x;
    if (idx >= 36864) return;
    const int i = idx & 7;
    const int lane = (idx >> 3) & 63;
    const int ot = (idx >> 9) & 3;
    const int h = (idx >> 11) & 1;
    const int j = idx >> 12;
    const int o = ot * 16 + (lane & 15);
    const int c = h * 32 + (lane >> 4) * 8 + i;
    bp[idx] = f2h(w[(o * 64 + c) * 9 + j]);
}

// ---- main: 16x16 output tile per block; halo staged in LDS (28x28, 32ch per pass) ----
// LDS layout (per h-half): position (ry,rx) -> 4 x 16B chunks at 16B-index
//   (ry*28+rx)*4 + (sub ^ (ry&3))
// swizzle mask is &3 (NOT &7): sub is a 2-bit chunk index, so XOR must stay
// within [0,4) to remain bijective inside the position's slot range. (&7 made
// rows with ry&4 spill into the neighbor position -> collisions at row-boundary
// wraps 7->8, 15->16, 23->24 == the round-6 absmax failure.)
__global__ __launch_bounds__(256, 2) void dcn_mfma(const unsigned short* __restrict__ xt,
                                                   const float* __restrict__ off,
                                                   const unsigned short* __restrict__ bp,
                                                   float* __restrict__ out) {
    __shared__ uint4 lds4[3136];   // 28*28*64B = 50176 B

    const int tid = threadIdx.x;
    const int lane = tid & 63;
    const int wid = tid >> 6;
    const int lrow = lane & 15;   // pixel within strip (A-row); o in epilogue
    const int lgrp = lane >> 4;   // k-group

    const int bid = blockIdx.x;
    const int n = bid & 7;               // XCD-pinned image
    const int tile = bid >> 3;           // 0..63
    const int t   = (tile >> 3) << 4;    // tile row origin
    const int tx0 = (tile & 7) << 4;     // tile col origin

    const unsigned short* xn = xt + (size_t)n * (HW * 64);
    const unsigned char* xb = (const unsigned char*)xn;
    const f16x8* bg = (const f16x8*)bp;
    const float* offn = off + (size_t)n * 18 * HW;

    f32x4 acc[4][4];
#pragma unroll
    for (int q = 0; q < 4; ++q)
#pragma unroll
        for (int r = 0; r < 4; ++r) acc[q][r] = (f32x4){0.f, 0.f, 0.f, 0.f};

#pragma unroll 1
    for (int h = 0; h < 2; ++h) {
        if (h) __syncthreads();   // all reads of previous half done before overwrite
        // ---- stage halo half (32 channels) : coalesced global -> LDS ----
        for (int c = tid; c < 784; c += 256) {
            const int ry = c / 28, rx = c - ry * 28;
            const int gy = min(max(t - 6 + ry, 0), 127);
            const int gx = min(max(tx0 - 6 + rx, 0), 127);
            const uint4* src = (const uint4*)(xn + ((((gy << 7) + gx) << 6) | (h << 5)));
            const int d = c << 2, sw = ry & 3;
#pragma unroll
            for (int sub = 0; sub < 4; ++sub) lds4[d + (sub ^ sw)] = src[sub];
        }
        __syncthreads();

        // ---- compute: 4 strips per wave, 9 taps, K-half h ----
#pragma unroll
        for (int q = 0; q < 4; ++q) {
            const int ho = t + wid * 4 + q;
            const int wo = tx0 + lrow;
            const int pix = (ho << 7) + wo;
            const float fho = (float)(ho - 1);
            const float fwo = (float)(wo - 1);

#pragma unroll 1
            for (int jo = 0; jo < 3; ++jo) {   // kh = jo
                const float* ob = offn + (size_t)(6 * jo) * HW + pix;
                const float o0 = ob[0];
                const float o1 = ob[(size_t)1 * HW];
                const float o2 = ob[(size_t)2 * HW];
                const float o3 = ob[(size_t)3 * HW];
                const float o4 = ob[(size_t)4 * HW];
                const float o5 = ob[(size_t)5 * HW];
#pragma unroll
                for (int ji = 0; ji < 3; ++ji) {   // kw = ji
                    const float oy = (ji == 0) ? o0 : (ji == 1) ? o2 : o4;
                    const float ox = (ji == 0) ? o1 : (ji == 1) ? o3 : o5;
                    const float py = fho + (float)jo + oy;
                    const float px = fwo + (float)ji + ox;
                    const float y0f = floorf(py), x0f = floorf(px);
                    const float wy = py - y0f, wx = px - x0f;
                    const int y0 = (int)y0f, xx0 = (int)x0f;
                    const bool vy0 = (unsigned)y0 < 128u;
                    const bool vy1 = (unsigned)(y0 + 1) < 128u;
                    const bool vx0 = (unsigned)xx0 < 128u;
                    const bool vx1 = (unsigned)(xx0 + 1) < 128u;
                    const int y0c = min(max(y0, 0), 127), y1c = min(max(y0 + 1, 0), 127);
                    const int x0c = min(max(xx0, 0), 127), x1c = min(max(xx0 + 1, 0), 127);
                    const float s00 = (1.f - wy) * (1.f - wx) * ((vy0 & vx0) ? 1.f : 0.f);
                    const float s01 = (1.f - wy) * wx * ((vy0 & vx1) ? 1.f : 0.f);
                    const float s10 = wy * (1.f - wx) * ((vy1 & vx0) ? 1.f : 0.f);
                    const float s11 = wy * wx * ((vy1 & vx1) ? 1.f : 0.f);
                    const _Float16 h00 = (_Float16)s00, h01 = (_Float16)s01;
                    const _Float16 h10 = (_Float16)s10, h11 = (_Float16)s11;
                    const f16x2 W00 = {h00, h00}, W01 = {h01, h01};
                    const f16x2 W10 = {h10, h10}, W11 = {h11, h11};

                    // in-halo slots
                    const int sy0 = y0c - t + 6, sy1 = y1c - t + 6;
                    const int sx0 = x0c - tx0 + 6, sx1 = x1c - tx0 + 6;
                    const bool ok = ((unsigned)sy0 <= 27u) & ((unsigned)sy1 <= 27u) &
                                    ((unsigned)sx0 <= 27u) & ((unsigned)sx1 <= 27u);
                    const int cy0 = min(max(sy0, 0), 27), cy1 = min(max(sy1, 0), 27);
                    const int cx0 = min(max(sx0, 0), 27), cx1 = min(max(sx1, 0), 27);
                    const int r0 = cy0 * 28, r1 = cy1 * 28;
                    const int g0 = lgrp ^ (cy0 & 3), g1 = lgrp ^ (cy1 & 3);
                    uint4 T00 = lds4[((r0 + cx0) << 2) + g0];
                    uint4 T01 = lds4[((r0 + cx1) << 2) + g0];
                    uint4 T10 = lds4[((r1 + cx0) << 2) + g1];
                    uint4 T11 = lds4[((r1 + cx1) << 2) + g1];
                    if (!__all(ok)) {   // ~never taken: offset beyond halo -> exact global path
                        if (!ok) {
                            const unsigned char* p = xb + ((((y0c << 7) + x0c) << 7) | (h << 6)) + (lgrp << 4);
                            const int dxo = (x1c - x0c) << 7;
                            const int dyo = (y1c - y0c) << 14;
                            T00 = *(const uint4*)p;
                            T01 = *(const uint4*)(p + dxo);
                            T10 = *(const uint4*)(p + dyo);
                            T11 = *(const uint4*)(p + dyo + dxo);
                        }
                    }
                    union { uint4 u; f16x2 h2[4]; f16x8 v; } A, U00, U01, U10, U11;
                    U00.u = T00; U01.u = T01; U10.u = T10; U11.u = T11;
#pragma unroll
                    for (int k = 0; k < 4; ++k)
                        A.h2[k] = U00.h2[k] * W00 + U01.h2[k] * W01
                                + U10.h2[k] * W10 + U11.h2[k] * W11;
                    const int j = jo * 3 + ji;
                    const int fb = ((j * 2 + h) << 8) + lane;   // ((j*2+h)*4)*64 + lane
                    acc[q][0] = __builtin_amdgcn_mfma_f32_16x16x32_f16(A.v, bg[fb],       acc[q][0], 0, 0, 0);
                    acc[q][1] = __builtin_amdgcn_mfma_f32_16x16x32_f16(A.v, bg[fb + 64],  acc[q][1], 0, 0, 0);
                    acc[q][2] = __builtin_amdgcn_mfma_f32_16x16x32_f16(A.v, bg[fb + 128], acc[q][2], 0, 0, 0);
                    acc[q][3] = __builtin_amdgcn_mfma_f32_16x16x32_f16(A.v, bg[fb + 192], acc[q][3], 0, 0, 0);
                }
            }
        }
    }

    // epilogue: o = qq*16 + lrow plane, pixel = strip_base + lgrp*4 + r (validated r2-r5)
#pragma unroll
    for (int q = 0; q < 4; ++q) {
        float* opb = out + (size_t)n * (O_ * HW) + ((t + wid * 4 + q) << 7) + tx0 + lgrp * 4;
        *(f32x4*)(opb + (size_t)(0 * 16 + lrow) * HW) = acc[q][0];
        *(f32x4*)(opb + (size_t)(1 * 16 + lrow) * HW) = acc[q][1];
        *(f32x4*)(opb + (size_t)(2 * 16 + lrow) * HW) = acc[q][2];
        *(f32x4*)(opb + (size_t)(3 * 16 + lrow) * HW) = acc[q][3];
    }
}

extern "C" void kernel_launch(void* const* d_in, const int* in_sizes, int n_in,
                              void* d_out, int out_size, void* d_ws, size_t ws_size,
                              hipStream_t stream) {
    const float* x = (const float*)d_in[0];
    const float* off = (const float*)d_in[1];
    const float* w = (const float*)d_in[2];
    float* out = (float*)d_out;

    unsigned short* bp = (unsigned short*)d_ws;                  // 73728 B
    unsigned short* xt = (unsigned short*)((char*)d_ws + 73728); // 16.8 MB

    bpack_kernel<<<144, 256, 0, stream>>>(w, bp);
    nchw2nhwc<<<4096, 256, 0, stream>>>(x, xt);

    dcn_mfma<<<512, 256, 0, stream>>>(xt, off, bp, out);
}